// Round 13
// baseline (167.422 us; speedup 1.0000x reference)
//
#include <hip/hip_runtime.h>

#define N_NODES 10000
#define N_EDGES 320000
#define DIM_IN  512
#define DIM_HID 128
#define HC      256   // HEADS*GC
#define NEG_SLOPE 0.2f
#define SLOT    96    // fixed CSR stride; max degree+1 ~ 59 << 96 (11 sigma)

typedef short short8 __attribute__((ext_vector_type(8)));
typedef float floatx4 __attribute__((ext_vector_type(4)));

__device__ __forceinline__ unsigned short f2bf(float x) {  // RNE fp32->bf16
  unsigned int u = __float_as_uint(x);
  u += 0x7FFFu + ((u >> 16) & 1u);
  return (unsigned short)(u >> 16);
}

// ---------------------------------------------------------------------------
// Prep (76 blocks): 0..11 = fp32 GEMM [W2;b2]@Wg -> WfT bf16 [256][128] +
// bfuse + cursor zeroing; 12..75 = W1 -> W1T bf16 [128][512] transpose.
// ---------------------------------------------------------------------------
__global__ __launch_bounds__(256) void prep_kernel(
    const float* __restrict__ W2, const float* __restrict__ Wg,
    const float* __restrict__ b2, const float* __restrict__ W1,
    unsigned short* __restrict__ WfT, float* __restrict__ bfuse,
    unsigned short* __restrict__ W1T, int* __restrict__ cursor) {
  __shared__ float Ast[16][68];
  __shared__ float Bsf[16][64];
  __shared__ unsigned short td[32][33];
  const int t = threadIdx.x;
  const int b = blockIdx.x;
  if (b < 12) {
    const int flat = b * 256 + t;
    if (flat < (N_NODES + 3) / 4) ((int4*)cursor)[flat] = make_int4(0, 0, 0, 0);
    const int bx = b >> 2, by = b & 3;
    const int tx = t & 15, ty = t >> 4;
    const int m0 = bx * 64, n0 = by * 64;
    const int ar = t >> 2, ac4 = (t & 3) * 4;
    const int br = t >> 4, bc4 = (t & 15) * 4;
    const int arow = m0 + ar;
    float acc[4][4] = {};
    float4 av, bv, avn, bvn;
    auto gload = [&](int k0, float4& a4, float4& b4) {
      if (arow < DIM_HID)       a4 = *(const float4*)(W2 + (size_t)arow * DIM_HID + k0 + ac4);
      else if (arow == DIM_HID) a4 = *(const float4*)(b2 + k0 + ac4);
      else                      a4 = make_float4(0.f, 0.f, 0.f, 0.f);
      b4 = *(const float4*)(Wg + (size_t)(k0 + br) * HC + n0 + bc4);
    };
    gload(0, av, bv);
    for (int k0 = 0; k0 < DIM_HID; k0 += 16) {
      Ast[ac4 + 0][ar] = av.x; Ast[ac4 + 1][ar] = av.y;
      Ast[ac4 + 2][ar] = av.z; Ast[ac4 + 3][ar] = av.w;
      *(float4*)&Bsf[br][bc4] = bv;
      __syncthreads();
      if (k0 + 16 < DIM_HID) gload(k0 + 16, avn, bvn);
#pragma unroll
      for (int kk = 0; kk < 16; ++kk) {
        const float4 a = *(const float4*)&Ast[kk][ty * 4];
        const float4 bq = *(const float4*)&Bsf[kk][tx * 4];
        const float as[4] = {a.x, a.y, a.z, a.w};
        const float bs[4] = {bq.x, bq.y, bq.z, bq.w};
#pragma unroll
        for (int i = 0; i < 4; ++i)
#pragma unroll
          for (int j = 0; j < 4; ++j) acc[i][j] = fmaf(as[i], bs[j], acc[i][j]);
      }
      __syncthreads();
      av = avn; bv = bvn;
    }
#pragma unroll
    for (int i = 0; i < 4; ++i) {
      const int row = m0 + ty * 4 + i;
#pragma unroll
      for (int j = 0; j < 4; ++j) {
        const int col = n0 + tx * 4 + j;
        if (row < DIM_HID)       WfT[(size_t)col * DIM_HID + row] = f2bf(acc[i][j]);
        else if (row == DIM_HID) bfuse[col] = acc[i][j];
      }
    }
  } else {
    const int bb = b - 12;  // 0..63
    const int r0 = (bb >> 2) * 32, c0 = (bb & 3) * 32;
    const int tx = t & 31, ty = t >> 5;
#pragma unroll
    for (int p = 0; p < 4; ++p)
      td[tx][ty + p * 8] = f2bf(W1[(size_t)(r0 + ty + p * 8) * DIM_HID + c0 + tx]);
    __syncthreads();
#pragma unroll
    for (int p = 0; p < 4; ++p)
      W1T[(size_t)(c0 + ty + p * 8) * DIM_IN + r0 + tx] = td[ty + p * 8][tx];
  }
}

// ---------------------------------------------------------------------------
// gemm1: h1b = bf16(relu(x @ W1 + b1)), bf16 MFMA, BM=32 BN=128 BK=32.
// 313 blocks; x (fp32) read ONCE, converted to bf16 during LDS staging.
// Wave w owns cols w*32..+31 (2 N-tiles) x 2 M-tiles -> 4 MFMA/K-iter.
// LDS rows padded to 40 ushorts (80 B) -> 2-way bank aliasing (free, m136).
// ---------------------------------------------------------------------------
__global__ __launch_bounds__(256) void gemm1_kernel(
    const float* __restrict__ x, const unsigned short* __restrict__ W1T,
    const float* __restrict__ b1, unsigned short* __restrict__ h1b) {
  constexpr int K = DIM_IN, N = DIM_HID, BK = 32;
  __shared__ unsigned short As[32][40];
  __shared__ unsigned short Bs[128][40];
  const int t = threadIdx.x;
  const int m0 = blockIdx.x * 32;
  const int w = t >> 6, L = t & 63, lm = L & 15, q = L >> 4;
  floatx4 acc[2][2] = {};
  const int arow = t >> 3, akoff = (t & 7) * 4;   // A: 32 rows x 32 k fp32
  const int bcol = t >> 1, bkoff = (t & 1) * 16;  // B: 128 cols x 32 k bf16
  float4 av, avn;
  uint4 vb0, vb1, vb0n, vb1n;
  auto ld = [&](int kb, float4& a4, uint4& b0, uint4& b1r) {
    a4 = (m0 + arow < N_NODES)
        ? *(const float4*)(x + (size_t)(m0 + arow) * K + kb + akoff)
        : make_float4(0.f, 0.f, 0.f, 0.f);
    b0  = *(const uint4*)(W1T + (size_t)bcol * K + kb + bkoff);
    b1r = *(const uint4*)(W1T + (size_t)bcol * K + kb + bkoff + 8);
  };
  constexpr int NT = K / BK;  // 16
  ld(0, av, vb0, vb1);
  for (int kt = 0; kt < NT; ++kt) {
    ushort4 s0 = {f2bf(av.x), f2bf(av.y), f2bf(av.z), f2bf(av.w)};
    *(ushort4*)&As[arow][akoff] = s0;
    *(uint4*)&Bs[bcol][bkoff]     = vb0;
    *(uint4*)&Bs[bcol][bkoff + 8] = vb1;
    __syncthreads();
    if (kt + 1 < NT) ld((kt + 1) * BK, avn, vb0n, vb1n);
    const short8 af0 = *(const short8*)&As[lm][q * 8];
    const short8 af1 = *(const short8*)&As[16 + lm][q * 8];
#pragma unroll
    for (int nt = 0; nt < 2; ++nt) {
      const short8 bf = *(const short8*)&Bs[w * 32 + nt * 16 + lm][q * 8];
      acc[0][nt] = __builtin_amdgcn_mfma_f32_16x16x32_bf16(af0, bf, acc[0][nt], 0, 0, 0);
      acc[1][nt] = __builtin_amdgcn_mfma_f32_16x16x32_bf16(af1, bf, acc[1][nt], 0, 0, 0);
    }
    __syncthreads();
    av = avn; vb0 = vb0n; vb1 = vb1n;
  }
#pragma unroll
  for (int mt = 0; mt < 2; ++mt) {
    const int row0 = m0 + mt * 16 + q * 4;
#pragma unroll
    for (int nt = 0; nt < 2; ++nt) {
      const int col = w * 32 + nt * 16 + lm;
      const float bv = b1[col];
#pragma unroll
      for (int r = 0; r < 4; ++r)
        if (row0 + r < N_NODES)
          h1b[(size_t)(row0 + r) * N + col] = f2bf(fmaxf(acc[mt][nt][r] + bv, 0.f));
    }
  }
}

// ---------------------------------------------------------------------------
// gemm2: g = bf16(h1b @ Wfuse + bfuse), BM=32 BN=256 BK=32, 313 blocks.
// h1b read once; wave w == head w (cols w*64..+63, 4 N-tiles) -> clean ATT
// epilogue. Preamble: slot-96 CSR scatter (cursor zeroed by prep).
// ---------------------------------------------------------------------------
__global__ __launch_bounds__(256) void gemm2_kernel(
    const unsigned short* __restrict__ h1b, const unsigned short* __restrict__ WfT,
    const float* __restrict__ bfuse, unsigned short* __restrict__ g,
    const float* __restrict__ att_src, const float* __restrict__ att_dst,
    float* __restrict__ a_src, float* __restrict__ a_dst,
    const int* __restrict__ e_src, const int* __restrict__ e_dst,
    int* __restrict__ cursor, int* __restrict__ src_sorted) {
  constexpr int K = DIM_HID, N = HC, BK = 32;
  __shared__ unsigned short As[32][40];
  __shared__ unsigned short Bs[256][40];
  const int t = threadIdx.x;
  {
    const int nthr = gridDim.x * 256;
    const int flat = blockIdx.x * 256 + t;
    for (int id = flat; id < N_EDGES + N_NODES; id += nthr) {
      int s, d;
      if (id < N_EDGES) { s = e_src[id]; d = e_dst[id]; }
      else              { s = d = id - N_EDGES; }
      src_sorted[d * SLOT + atomicAdd(&cursor[d], 1)] = s;
    }
  }
  const int m0 = blockIdx.x * 32;
  const int w = t >> 6, L = t & 63, lm = L & 15, q = L >> 4;
  floatx4 acc[2][4] = {};
  const int arow = t >> 3, akoff = (t & 7) * 4;   // A: 32 rows, uint2 (4 bf16)
  uint2 va, van;
  uint4 vb[4], vbn[4];
  auto ld = [&](int kb, uint2& a2, uint4* b4) {
    a2 = *(const uint2*)(h1b + (size_t)(m0 + arow) * K + kb + akoff);
#pragma unroll
    for (int j = 0; j < 4; ++j)
      b4[j] = *(const uint4*)(WfT + (size_t)t * K + kb + j * 8);
  };
  constexpr int NT = K / BK;  // 4
  ld(0, va, vb);
  for (int kt = 0; kt < NT; ++kt) {
    *(uint2*)&As[arow][akoff] = va;
#pragma unroll
    for (int j = 0; j < 4; ++j) *(uint4*)&Bs[t][j * 8] = vb[j];
    __syncthreads();
    if (kt + 1 < NT) ld((kt + 1) * BK, van, vbn);
    const short8 af0 = *(const short8*)&As[lm][q * 8];
    const short8 af1 = *(const short8*)&As[16 + lm][q * 8];
#pragma unroll
    for (int nt = 0; nt < 4; ++nt) {
      const short8 bf = *(const short8*)&Bs[w * 64 + nt * 16 + lm][q * 8];
      acc[0][nt] = __builtin_amdgcn_mfma_f32_16x16x32_bf16(af0, bf, acc[0][nt], 0, 0, 0);
      acc[1][nt] = __builtin_amdgcn_mfma_f32_16x16x32_bf16(af1, bf, acc[1][nt], 0, 0, 0);
    }
    __syncthreads();
    va = van;
#pragma unroll
    for (int j = 0; j < 4; ++j) vb[j] = vbn[j];
  }
  // epilogue: head == wave w; bias + bf16 g + attention scores
  float ps[2][4] = {}, pd[2][4] = {};
#pragma unroll
  for (int nt = 0; nt < 4; ++nt) {
    const int col = w * 64 + nt * 16 + lm;
    const float bv = bfuse[col];
    const float as_c = att_src[col];   // att_src[h][c] flat == col since head=w
    const float ad_c = att_dst[col];
#pragma unroll
    for (int mt = 0; mt < 2; ++mt) {
      const int row0 = m0 + mt * 16 + q * 4;
#pragma unroll
      for (int r = 0; r < 4; ++r) {
        const float gv = acc[mt][nt][r] + bv;
        if (row0 + r < N_NODES) g[(size_t)(row0 + r) * N + col] = f2bf(gv);
        ps[mt][r] = fmaf(gv, as_c, ps[mt][r]);
        pd[mt][r] = fmaf(gv, ad_c, pd[mt][r]);
      }
    }
  }
#pragma unroll
  for (int mt = 0; mt < 2; ++mt) {
    const int row0 = m0 + mt * 16 + q * 4;
#pragma unroll
    for (int r = 0; r < 4; ++r) {
#pragma unroll
      for (int off = 1; off < 16; off <<= 1) {
        ps[mt][r] += __shfl_xor(ps[mt][r], off);
        pd[mt][r] += __shfl_xor(pd[mt][r], off);
      }
      if (lm == 0 && row0 + r < N_NODES) {
        a_src[(row0 + r) * 4 + w] = ps[mt][r];
        a_dst[(row0 + r) * 4 + w] = pd[mt][r];
      }
    }
  }
}

// ---------------------------------------------------------------------------
// Aggregate: one wave per node, zero barriers / zero LDS (R11/R12 winner).
// start = node*SLOT, end = start + cursor[node] (slot-96 CSR). unroll 8.
// ---------------------------------------------------------------------------
__global__ __launch_bounds__(256) void aggregate_kernel(
    const unsigned short* __restrict__ g, const float* __restrict__ a_src,
    const float* __restrict__ a_dst, const int* __restrict__ cursor,
    const int* __restrict__ src_sorted, const float* __restrict__ bias_g,
    float* __restrict__ out) {
  const int wv   = threadIdx.x >> 6;
  const int lane = threadIdx.x & 63;
  const int node = blockIdx.x * 4 + wv;
  if (node >= N_NODES) return;
  const int e2 = lane >> 5;     // edge parity
  const int c8 = lane & 31;     // chan-octet (chans c8*8 .. +7)
  const int h  = c8 >> 3;       // head of those chans
  const int start = node * SLOT;
  const int end   = start + cursor[node];
  const float4 ad = *(const float4*)(a_dst + node * 4);

  float a[8] = {};
  float s_loc = 0.f;
  for (int base = start; base < end; base += 64) {
    const int rem = min(64, end - base);
    int   sidxL = 0;
    float w0 = 0.f, w1 = 0.f, w2 = 0.f, w3 = 0.f;
    if (lane < rem) {
      sidxL = src_sorted[base + lane];
      const float4 as4 = *(const float4*)(a_src + sidxL * 4);
      float e0 = as4.x + ad.x; e0 = (e0 > 0.f) ? e0 : NEG_SLOPE * e0;
      float e1 = as4.y + ad.y; e1 = (e1 > 0.f) ? e1 : NEG_SLOPE * e1;
      float ee = as4.z + ad.z; ee = (ee > 0.f) ? ee : NEG_SLOPE * ee;
      float e3 = as4.w + ad.w; e3 = (e3 > 0.f) ? e3 : NEG_SLOPE * e3;
      w0 = __expf(e0); w1 = __expf(e1); w2 = __expf(ee); w3 = __expf(e3);
    }
    const int half = (rem + 1) >> 1;
#pragma unroll 8
    for (int k = 0; k < half; ++k) {
      const int j  = 2 * k + e2;
      const int js = (j < rem) ? j : (rem - 1);      // keep shfl src valid
      const int sj = __shfl(sidxL, js);
      const float f0 = __shfl(w0, js), f1 = __shfl(w1, js);
      const float f2 = __shfl(w2, js), f3 = __shfl(w3, js);
      float w = (h & 2) ? ((h & 1) ? f3 : f2) : ((h & 1) ? f1 : f0);
      if (j >= rem) w = 0.f;                          // masked tail edge
      const uint4 gv = *(const uint4*)(g + (size_t)sj * HC + c8 * 8);
      s_loc += w;
      a[0] = fmaf(w, __uint_as_float(gv.x << 16), a[0]);
      a[1] = fmaf(w, __uint_as_float(gv.x & 0xFFFF0000u), a[1]);
      a[2] = fmaf(w, __uint_as_float(gv.y << 16), a[2]);
      a[3] = fmaf(w, __uint_as_float(gv.y & 0xFFFF0000u), a[3]);
      a[4] = fmaf(w, __uint_as_float(gv.z << 16), a[4]);
      a[5] = fmaf(w, __uint_as_float(gv.z & 0xFFFF0000u), a[5]);
      a[6] = fmaf(w, __uint_as_float(gv.w << 16), a[6]);
      a[7] = fmaf(w, __uint_as_float(gv.w & 0xFFFF0000u), a[7]);
    }
  }
#pragma unroll
  for (int k = 0; k < 8; ++k) a[k] += __shfl_xor(a[k], 32);
  s_loc += __shfl_xor(s_loc, 32);
  if (e2 == 0) {
    const float inv = 1.f / s_loc;
    const float4 b0 = *(const float4*)(bias_g + c8 * 8);
    const float4 b1v = *(const float4*)(bias_g + c8 * 8 + 4);
    float4 o0, o1;
    o0.x = a[0] * inv + b0.x;  o0.y = a[1] * inv + b0.y;
    o0.z = a[2] * inv + b0.z;  o0.w = a[3] * inv + b0.w;
    o1.x = a[4] * inv + b1v.x; o1.y = a[5] * inv + b1v.y;
    o1.z = a[6] * inv + b1v.z; o1.w = a[7] * inv + b1v.w;
    float* op = out + (size_t)node * HC + c8 * 8;
    *(float4*)op = o0;
    *(float4*)(op + 4) = o1;
  }
}

// ---------------------------------------------------------------------------
extern "C" void kernel_launch(void* const* d_in, const int* in_sizes, int n_in,
                              void* d_out, int out_size, void* d_ws, size_t ws_size,
                              hipStream_t stream) {
  const float* x       = (const float*)d_in[0];
  const int*   ei      = (const int*)d_in[1];   // [2,E] int32: src then dst
  const float* W1      = (const float*)d_in[2];
  const float* b1      = (const float*)d_in[3];
  const float* W2      = (const float*)d_in[4];
  const float* b2      = (const float*)d_in[5];
  const float* Wg      = (const float*)d_in[6];
  const float* att_src = (const float*)d_in[7];
  const float* att_dst = (const float*)d_in[8];
  const float* bias_g  = (const float*)d_in[9];
  float* out = (float*)d_out;

  char* ws = (char*)d_ws;
  unsigned short* h1b = (unsigned short*)ws; ws += (size_t)(N_NODES + 64) * DIM_HID * 2;
  unsigned short* g   = (unsigned short*)ws; ws += (size_t)N_NODES * HC * 2;
  unsigned short* W1T = (unsigned short*)ws; ws += (size_t)DIM_HID * DIM_IN * 2;
  unsigned short* WfT = (unsigned short*)ws; ws += (size_t)HC * DIM_HID * 2;
  float* bfuse   = (float*)ws; ws += (size_t)HC * 4;
  float* a_src   = (float*)ws; ws += (size_t)N_NODES * 4 * 4;
  float* a_dst   = (float*)ws; ws += (size_t)N_NODES * 4 * 4;
  int* cursor    = (int*)ws;   ws += (size_t)N_NODES * 4;
  int* src_sorted= (int*)ws;   ws += (size_t)N_NODES * SLOT * 4;

  const dim3 blk(256);
  // 1. prep: WfT+bfuse GEMM, W1T transpose, cursor zero
  prep_kernel<<<76, blk, 0, stream>>>(W2, Wg, b2, W1, WfT, bfuse, W1T, cursor);
  // 2. encoder layer 1 MFMA (x read once, fp32->bf16 staging)
  gemm1_kernel<<<313, blk, 0, stream>>>(x, W1T, b1, h1b);
  // 3. fused layer2+GAT MFMA -> bf16 g + attention epilogue + slot-96 scatter
  gemm2_kernel<<<313, blk, 0, stream>>>(
      h1b, WfT, bfuse, g, att_src, att_dst, a_src, a_dst,
      ei, ei + N_EDGES, cursor, src_sorted);
  // 4. segment softmax + weighted aggregate (wave per node)
  aggregate_kernel<<<(N_NODES + 3) / 4, blk, 0, stream>>>(
      g, a_src, a_dst, cursor, src_sorted, bias_g, out);
}

// Round 14
// 152.191 us; speedup vs baseline: 1.1001x; 1.1001x over previous
//
#include <hip/hip_runtime.h>

#define N_NODES 10000
#define N_EDGES 320000
#define DIM_IN  512
#define DIM_HID 128
#define HC      256   // HEADS*GC
#define NEG_SLOPE 0.2f
#define SLOT    96    // fixed CSR stride; max degree+1 ~ 59 << 96 (11 sigma)

typedef short short8 __attribute__((ext_vector_type(8)));
typedef float floatx4 __attribute__((ext_vector_type(4)));

__device__ __forceinline__ unsigned short f2bf(float x) {  // RNE fp32->bf16
  unsigned int u = __float_as_uint(x);
  u += 0x7FFFu + ((u >> 16) & 1u);
  return (unsigned short)(u >> 16);
}

// ---------------------------------------------------------------------------
// Prep (one launch):
//   blocks 0..11   : fp32 GEMM [W2;b2]@Wg -> WfT (bf16 [256][128]) + bfuse,
//                    plus cursor zeroing
//   blocks 12..75  : W1 [512][128] -> W1T bf16 [128][512] tile transpose
//   blocks 76..2575: x fp32 -> xb bf16 (5.12M elems, 8/thread)
// ---------------------------------------------------------------------------
__global__ __launch_bounds__(256) void prep_kernel(
    const float* __restrict__ W2, const float* __restrict__ Wg,
    const float* __restrict__ b2, const float* __restrict__ W1,
    const float* __restrict__ x,
    unsigned short* __restrict__ WfT, float* __restrict__ bfuse,
    unsigned short* __restrict__ W1T, unsigned short* __restrict__ xb,
    int* __restrict__ cursor) {
  __shared__ float Ast[16][68];
  __shared__ float Bsf[16][64];
  __shared__ unsigned short td[32][33];
  const int t = threadIdx.x;
  const int b = blockIdx.x;
  if (b >= 76) {  // x -> bf16
    const int base = (b - 76) * 2048 + t * 8;
    const float4 v0 = *(const float4*)(x + base);
    const float4 v1 = *(const float4*)(x + base + 4);
    ushort4 s0 = {f2bf(v0.x), f2bf(v0.y), f2bf(v0.z), f2bf(v0.w)};
    ushort4 s1 = {f2bf(v1.x), f2bf(v1.y), f2bf(v1.z), f2bf(v1.w)};
    *(ushort4*)(xb + base)     = s0;
    *(ushort4*)(xb + base + 4) = s1;
    return;
  }
  if (b < 12) {
    const int flat = b * 256 + t;
    if (flat < (N_NODES + 3) / 4) ((int4*)cursor)[flat] = make_int4(0, 0, 0, 0);
    const int bx = b >> 2, by = b & 3;
    const int tx = t & 15, ty = t >> 4;
    const int m0 = bx * 64, n0 = by * 64;
    const int ar = t >> 2, ac4 = (t & 3) * 4;
    const int br = t >> 4, bc4 = (t & 15) * 4;
    const int arow = m0 + ar;
    float acc[4][4] = {};
    float4 av, bv, avn, bvn;
    auto gload = [&](int k0, float4& a4, float4& b4) {
      if (arow < DIM_HID)       a4 = *(const float4*)(W2 + (size_t)arow * DIM_HID + k0 + ac4);
      else if (arow == DIM_HID) a4 = *(const float4*)(b2 + k0 + ac4);
      else                      a4 = make_float4(0.f, 0.f, 0.f, 0.f);
      b4 = *(const float4*)(Wg + (size_t)(k0 + br) * HC + n0 + bc4);
    };
    gload(0, av, bv);
    for (int k0 = 0; k0 < DIM_HID; k0 += 16) {
      Ast[ac4 + 0][ar] = av.x; Ast[ac4 + 1][ar] = av.y;
      Ast[ac4 + 2][ar] = av.z; Ast[ac4 + 3][ar] = av.w;
      *(float4*)&Bsf[br][bc4] = bv;
      __syncthreads();
      if (k0 + 16 < DIM_HID) gload(k0 + 16, avn, bvn);
#pragma unroll
      for (int kk = 0; kk < 16; ++kk) {
        const float4 a = *(const float4*)&Ast[kk][ty * 4];
        const float4 bq = *(const float4*)&Bsf[kk][tx * 4];
        const float as[4] = {a.x, a.y, a.z, a.w};
        const float bs[4] = {bq.x, bq.y, bq.z, bq.w};
#pragma unroll
        for (int i = 0; i < 4; ++i)
#pragma unroll
          for (int j = 0; j < 4; ++j) acc[i][j] = fmaf(as[i], bs[j], acc[i][j]);
      }
      __syncthreads();
      av = avn; bv = bvn;
    }
#pragma unroll
    for (int i = 0; i < 4; ++i) {
      const int row = m0 + ty * 4 + i;
#pragma unroll
      for (int j = 0; j < 4; ++j) {
        const int col = n0 + tx * 4 + j;
        if (row < DIM_HID)       WfT[(size_t)col * DIM_HID + row] = f2bf(acc[i][j]);
        else if (row == DIM_HID) bfuse[col] = acc[i][j];
      }
    }
  } else {
    const int bb = b - 12;  // 0..63
    const int r0 = (bb >> 2) * 32, c0 = (bb & 3) * 32;
    const int tx = t & 31, ty = t >> 5;
#pragma unroll
    for (int p = 0; p < 4; ++p)
      td[tx][ty + p * 8] = f2bf(W1[(size_t)(r0 + ty + p * 8) * DIM_HID + c0 + tx]);
    __syncthreads();
#pragma unroll
    for (int p = 0; p < 4; ++p)
      W1T[(size_t)(c0 + ty + p * 8) * DIM_IN + r0 + tx] = td[ty + p * 8][tx];
  }
}

// ---------------------------------------------------------------------------
// gemm1: h1b = bf16(relu(xb @ W1 + b1)), all-bf16 MFMA, BM=64 BN=32 BK=32.
// 157x4 = 628 blocks (2.45/CU — R13 lesson: schedule granularity beats
// L2-traffic savings; 313 heavier blocks regressed 15 us).
// ---------------------------------------------------------------------------
__global__ __launch_bounds__(256) void gemm1_kernel(
    const unsigned short* __restrict__ xb, const unsigned short* __restrict__ W1T,
    const float* __restrict__ b1, unsigned short* __restrict__ h1b) {
  constexpr int K = DIM_IN, N = DIM_HID, BK = 32;
  __shared__ unsigned short As[64][48];
  __shared__ unsigned short Bs[32][48];
  const int t = threadIdx.x;
  const int m0 = blockIdx.x * 64, n0 = blockIdx.y * 32;
  const int w = t >> 6, L = t & 63, lm = L & 15, q = L >> 4;
  floatx4 acc[2] = {};
  uint4 ab, abn;
  uint2 bb, bbn;
  auto ld = [&](int kb, uint4& va, uint2& vb) {
    va = *(const uint4*)(xb + (size_t)(m0 + (t >> 2)) * K + kb + (t & 3) * 8);
    vb = *(const uint2*)(W1T + (size_t)(n0 + (t >> 3)) * K + kb + (t & 7) * 4);
  };
  constexpr int NT = K / BK;  // 16
  ld(0, ab, bb);
  for (int kt = 0; kt < NT; ++kt) {
    *(uint4*)&As[t >> 2][(t & 3) * 8] = ab;
    *(uint2*)&Bs[t >> 3][(t & 7) * 4] = bb;
    __syncthreads();
    if (kt + 1 < NT) ld((kt + 1) * BK, abn, bbn);
    const short8 af = *(const short8*)&As[w * 16 + lm][q * 8];
#pragma unroll
    for (int nt = 0; nt < 2; ++nt) {
      const short8 bf = *(const short8*)&Bs[nt * 16 + lm][q * 8];
      acc[nt] = __builtin_amdgcn_mfma_f32_16x16x32_bf16(af, bf, acc[nt], 0, 0, 0);
    }
    __syncthreads();
    ab = abn; bb = bbn;
  }
  const int row0 = m0 + w * 16 + q * 4;
#pragma unroll
  for (int nt = 0; nt < 2; ++nt) {
    const int col = n0 + nt * 16 + lm;
    const float bv = b1[col];
#pragma unroll
    for (int r = 0; r < 4; ++r)
      if (row0 + r < N_NODES)
        h1b[(size_t)(row0 + r) * N + col] = f2bf(fmaxf(acc[nt][r] + bv, 0.f));
  }
}

// ---------------------------------------------------------------------------
// gemm2: g = bf16(h1b @ Wfuse + bfuse), BM=BN=64 BK=32, ATT epilogue.
// Preamble: slot-96 CSR scatter (cursor zeroed by prep; no scan needed).
// ---------------------------------------------------------------------------
__global__ __launch_bounds__(256) void gemm2_kernel(
    const unsigned short* __restrict__ h1b, const unsigned short* __restrict__ WfT,
    const float* __restrict__ bfuse, unsigned short* __restrict__ g,
    const float* __restrict__ att_src, const float* __restrict__ att_dst,
    float* __restrict__ a_src, float* __restrict__ a_dst,
    const int* __restrict__ e_src, const int* __restrict__ e_dst,
    int* __restrict__ cursor, int* __restrict__ src_sorted) {
  constexpr int K = DIM_HID, N = HC, BK = 32;
  __shared__ unsigned short As[64][48];
  __shared__ unsigned short Bs[64][48];
  const int t = threadIdx.x;
  {
    const int nthr = gridDim.x * gridDim.y * 256;
    const int flat = (blockIdx.y * gridDim.x + blockIdx.x) * 256 + t;
    for (int id = flat; id < N_EDGES + N_NODES; id += nthr) {
      int s, d;
      if (id < N_EDGES) { s = e_src[id]; d = e_dst[id]; }
      else              { s = d = id - N_EDGES; }
      src_sorted[d * SLOT + atomicAdd(&cursor[d], 1)] = s;
    }
  }
  const int m0 = blockIdx.x * 64, n0 = blockIdx.y * 64;
  const int w = t >> 6, L = t & 63, lm = L & 15, q = L >> 4;
  floatx4 acc[4] = {};
  uint4 ab, abn, bb, bbn;
  auto ld = [&](int kb, uint4& va, uint4& vb) {
    va = *(const uint4*)(h1b + (size_t)(m0 + (t >> 2)) * K + kb + (t & 3) * 8);
    vb = *(const uint4*)(WfT + (size_t)(n0 + (t >> 2)) * K + kb + (t & 3) * 8);
  };
  constexpr int NT = K / BK;  // 4
  ld(0, ab, bb);
  for (int kt = 0; kt < NT; ++kt) {
    *(uint4*)&As[t >> 2][(t & 3) * 8] = ab;
    *(uint4*)&Bs[t >> 2][(t & 3) * 8] = bb;
    __syncthreads();
    if (kt + 1 < NT) ld((kt + 1) * BK, abn, bbn);
    const short8 af = *(const short8*)&As[w * 16 + lm][q * 8];
#pragma unroll
    for (int nt = 0; nt < 4; ++nt) {
      const short8 bf = *(const short8*)&Bs[nt * 16 + lm][q * 8];
      acc[nt] = __builtin_amdgcn_mfma_f32_16x16x32_bf16(af, bf, acc[nt], 0, 0, 0);
    }
    __syncthreads();
    ab = abn; bb = bbn;
  }
  const int row0 = m0 + w * 16 + q * 4;
  const int hh = n0 >> 6;
  float ps[4] = {}, pd[4] = {};
#pragma unroll
  for (int nt = 0; nt < 4; ++nt) {
    const int col = n0 + nt * 16 + lm;
    const float bv = bfuse[col];
    const float as_c = att_src[hh * 64 + nt * 16 + lm];
    const float ad_c = att_dst[hh * 64 + nt * 16 + lm];
#pragma unroll
    for (int r = 0; r < 4; ++r) {
      const float gv = acc[nt][r] + bv;
      if (row0 + r < N_NODES) g[(size_t)(row0 + r) * N + col] = f2bf(gv);
      ps[r] = fmaf(gv, as_c, ps[r]);
      pd[r] = fmaf(gv, ad_c, pd[r]);
    }
  }
#pragma unroll
  for (int r = 0; r < 4; ++r) {
#pragma unroll
    for (int off = 1; off < 16; off <<= 1) {
      ps[r] += __shfl_xor(ps[r], off);
      pd[r] += __shfl_xor(pd[r], off);
    }
    if (lm == 0 && row0 + r < N_NODES) {
      a_src[(row0 + r) * 4 + hh] = ps[r];
      a_dst[(row0 + r) * 4 + hh] = pd[r];
    }
  }
}

// ---------------------------------------------------------------------------
// Aggregate: one wave per node, zero barriers / zero LDS (R11/R12 winner).
// start = node*SLOT, end = start + cursor[node] (slot-96 CSR).
// ---------------------------------------------------------------------------
__global__ __launch_bounds__(256) void aggregate_kernel(
    const unsigned short* __restrict__ g, const float* __restrict__ a_src,
    const float* __restrict__ a_dst, const int* __restrict__ cursor,
    const int* __restrict__ src_sorted, const float* __restrict__ bias_g,
    float* __restrict__ out) {
  const int wv   = threadIdx.x >> 6;
  const int lane = threadIdx.x & 63;
  const int node = blockIdx.x * 4 + wv;
  if (node >= N_NODES) return;
  const int e2 = lane >> 5;     // edge parity
  const int c8 = lane & 31;     // chan-octet (chans c8*8 .. +7)
  const int h  = c8 >> 3;       // head of those chans
  const int start = node * SLOT;
  const int end   = start + cursor[node];
  const float4 ad = *(const float4*)(a_dst + node * 4);

  float a[8] = {};
  float s_loc = 0.f;
  for (int base = start; base < end; base += 64) {
    const int rem = min(64, end - base);
    int   sidxL = 0;
    float w0 = 0.f, w1 = 0.f, w2 = 0.f, w3 = 0.f;
    if (lane < rem) {
      sidxL = src_sorted[base + lane];
      const float4 as4 = *(const float4*)(a_src + sidxL * 4);
      float e0 = as4.x + ad.x; e0 = (e0 > 0.f) ? e0 : NEG_SLOPE * e0;
      float e1 = as4.y + ad.y; e1 = (e1 > 0.f) ? e1 : NEG_SLOPE * e1;
      float ee = as4.z + ad.z; ee = (ee > 0.f) ? ee : NEG_SLOPE * ee;
      float e3 = as4.w + ad.w; e3 = (e3 > 0.f) ? e3 : NEG_SLOPE * e3;
      w0 = __expf(e0); w1 = __expf(e1); w2 = __expf(ee); w3 = __expf(e3);
    }
    const int half = (rem + 1) >> 1;
#pragma unroll 4
    for (int k = 0; k < half; ++k) {
      const int j  = 2 * k + e2;
      const int js = (j < rem) ? j : (rem - 1);      // keep shfl src valid
      const int sj = __shfl(sidxL, js);
      const float f0 = __shfl(w0, js), f1 = __shfl(w1, js);
      const float f2 = __shfl(w2, js), f3 = __shfl(w3, js);
      float w = (h & 2) ? ((h & 1) ? f3 : f2) : ((h & 1) ? f1 : f0);
      if (j >= rem) w = 0.f;                          // masked tail edge
      const uint4 gv = *(const uint4*)(g + (size_t)sj * HC + c8 * 8);
      s_loc += w;
      a[0] = fmaf(w, __uint_as_float(gv.x << 16), a[0]);
      a[1] = fmaf(w, __uint_as_float(gv.x & 0xFFFF0000u), a[1]);
      a[2] = fmaf(w, __uint_as_float(gv.y << 16), a[2]);
      a[3] = fmaf(w, __uint_as_float(gv.y & 0xFFFF0000u), a[3]);
      a[4] = fmaf(w, __uint_as_float(gv.z << 16), a[4]);
      a[5] = fmaf(w, __uint_as_float(gv.z & 0xFFFF0000u), a[5]);
      a[6] = fmaf(w, __uint_as_float(gv.w << 16), a[6]);
      a[7] = fmaf(w, __uint_as_float(gv.w & 0xFFFF0000u), a[7]);
    }
  }
#pragma unroll
  for (int k = 0; k < 8; ++k) a[k] += __shfl_xor(a[k], 32);
  s_loc += __shfl_xor(s_loc, 32);
  if (e2 == 0) {
    const float inv = 1.f / s_loc;
    const float4 b0 = *(const float4*)(bias_g + c8 * 8);
    const float4 b1v = *(const float4*)(bias_g + c8 * 8 + 4);
    float4 o0, o1;
    o0.x = a[0] * inv + b0.x;  o0.y = a[1] * inv + b0.y;
    o0.z = a[2] * inv + b0.z;  o0.w = a[3] * inv + b0.w;
    o1.x = a[4] * inv + b1v.x; o1.y = a[5] * inv + b1v.y;
    o1.z = a[6] * inv + b1v.z; o1.w = a[7] * inv + b1v.w;
    float* op = out + (size_t)node * HC + c8 * 8;
    *(float4*)op = o0;
    *(float4*)(op + 4) = o1;
  }
}

// ---------------------------------------------------------------------------
extern "C" void kernel_launch(void* const* d_in, const int* in_sizes, int n_in,
                              void* d_out, int out_size, void* d_ws, size_t ws_size,
                              hipStream_t stream) {
  const float* x       = (const float*)d_in[0];
  const int*   ei      = (const int*)d_in[1];   // [2,E] int32: src then dst
  const float* W1      = (const float*)d_in[2];
  const float* b1      = (const float*)d_in[3];
  const float* W2      = (const float*)d_in[4];
  const float* b2      = (const float*)d_in[5];
  const float* Wg      = (const float*)d_in[6];
  const float* att_src = (const float*)d_in[7];
  const float* att_dst = (const float*)d_in[8];
  const float* bias_g  = (const float*)d_in[9];
  float* out = (float*)d_out;

  char* ws = (char*)d_ws;
  unsigned short* xb  = (unsigned short*)ws; ws += (size_t)(N_NODES + 64) * DIM_IN * 2;
  unsigned short* h1b = (unsigned short*)ws; ws += (size_t)(N_NODES + 64) * DIM_HID * 2;
  unsigned short* g   = (unsigned short*)ws; ws += (size_t)N_NODES * HC * 2;
  unsigned short* W1T = (unsigned short*)ws; ws += (size_t)DIM_HID * DIM_IN * 2;
  unsigned short* WfT = (unsigned short*)ws; ws += (size_t)HC * DIM_HID * 2;
  float* bfuse   = (float*)ws; ws += (size_t)HC * 4;
  float* a_src   = (float*)ws; ws += (size_t)N_NODES * 4 * 4;
  float* a_dst   = (float*)ws; ws += (size_t)N_NODES * 4 * 4;
  int* cursor    = (int*)ws;   ws += (size_t)N_NODES * 4;
  int* src_sorted= (int*)ws;   ws += (size_t)N_NODES * SLOT * 4;

  const dim3 blk(256);
  // 1. prep: WfT+bfuse GEMM, W1T transpose, x->bf16, cursor zero
  prep_kernel<<<76 + 2500, blk, 0, stream>>>(
      W2, Wg, b2, W1, x, WfT, bfuse, W1T, xb, cursor);
  // 2. encoder layer 1 MFMA (all-bf16) + relu/bias epilogue
  gemm1_kernel<<<dim3(157, 4), blk, 0, stream>>>(xb, W1T, b1, h1b);
  // 3. fused layer2+GAT MFMA -> bf16 g, attention epilogue, + slot-96 scatter
  gemm2_kernel<<<dim3(157, 4), blk, 0, stream>>>(
      h1b, WfT, bfuse, g, att_src, att_dst, a_src, a_dst,
      ei, ei + N_EDGES, cursor, src_sorted);
  // 4. segment softmax + weighted aggregate (wave per node)
  aggregate_kernel<<<(N_NODES + 3) / 4, blk, 0, stream>>>(
      g, a_src, a_dst, cursor, src_sorted, bias_g, out);
}

// Round 15
// 151.724 us; speedup vs baseline: 1.1035x; 1.0031x over previous
//
#include <hip/hip_runtime.h>

#define N_NODES 10000
#define N_EDGES 320000
#define DIM_IN  512
#define DIM_HID 128
#define HC      256   // HEADS*GC
#define NEG_SLOPE 0.2f
#define SLOT    96    // fixed CSR stride; max degree+1 ~ 59 << 96 (11 sigma)

typedef short short8 __attribute__((ext_vector_type(8)));
typedef float floatx4 __attribute__((ext_vector_type(4)));

__device__ __forceinline__ unsigned short f2bf(float x) {  // RNE fp32->bf16
  unsigned int u = __float_as_uint(x);
  u += 0x7FFFu + ((u >> 16) & 1u);
  return (unsigned short)(u >> 16);
}

// ---------------------------------------------------------------------------
// fused1 (ONE launch, 640 blocks):
//   blocks 0..627  : gemm1 tile — h1b = bf16(relu(x @ W1 + b1)), bf16 MFMA,
//                    BM=64 BN=32 BK=32, 4 strips (R13 lesson: 628 light
//                    blocks beat 313 heavy ones). A staged fp32->bf16 from x
//                    directly; B staged from natural-layout W1 via in-LDS
//                    transpose (kills the xb conversion pass AND W1T).
//   blocks 628..639: prep GEMM [W2;b2]@Wg -> WfT bf16 [256][128] + bfuse
//                    + cursor zeroing (consumed by the NEXT launch only, so
//                    it can share this dispatch).
// ---------------------------------------------------------------------------
union Sm1 {
  struct { unsigned short As[64][48]; unsigned short Bs[32][48]; } g;  // 9216 B
  struct { float Ast[16][68]; float Bsf[16][64]; } p;                  // 8448 B
};

__global__ __launch_bounds__(256) void fused1_kernel(
    const float* __restrict__ x, const float* __restrict__ W1,
    const float* __restrict__ b1,
    const float* __restrict__ W2, const float* __restrict__ Wg,
    const float* __restrict__ b2,
    unsigned short* __restrict__ h1b, unsigned short* __restrict__ WfT,
    float* __restrict__ bfuse, int* __restrict__ cursor) {
  __shared__ Sm1 sm;
  const int t = threadIdx.x;
  const int b = blockIdx.x;

  if (b < 628) {
    constexpr int K = DIM_IN, N = DIM_HID, BK = 32;
    const int m0 = (b % 157) * 64, n0 = (b / 157) * 32;
    const int w = t >> 6, L = t & 63, lm = L & 15, q = L >> 4;
    floatx4 acc[2] = {};
    const int ar = t >> 3, ac = (t & 7) * 4;   // A rows ar/ar+32, k-off ac;
                                               // B k-row ar, n-off ac
    float4 va0, va1, vb, va0n, va1n, vbn;
    auto ld = [&](int kb, float4& a0, float4& a1, float4& bw) {
      a0 = (m0 + ar < N_NODES)
          ? *(const float4*)(x + (size_t)(m0 + ar) * K + kb + ac)
          : make_float4(0.f, 0.f, 0.f, 0.f);
      a1 = (m0 + ar + 32 < N_NODES)
          ? *(const float4*)(x + (size_t)(m0 + ar + 32) * K + kb + ac)
          : make_float4(0.f, 0.f, 0.f, 0.f);
      bw = *(const float4*)(W1 + (size_t)(kb + ar) * N + n0 + ac);
    };
    constexpr int NT = K / BK;  // 16
    ld(0, va0, va1, vb);
    for (int kt = 0; kt < NT; ++kt) {
      ushort4 s0 = {f2bf(va0.x), f2bf(va0.y), f2bf(va0.z), f2bf(va0.w)};
      ushort4 s1 = {f2bf(va1.x), f2bf(va1.y), f2bf(va1.z), f2bf(va1.w)};
      *(ushort4*)&sm.g.As[ar][ac]      = s0;
      *(ushort4*)&sm.g.As[ar + 32][ac] = s1;
      sm.g.Bs[ac + 0][ar] = f2bf(vb.x);   // in-LDS transpose of W1 tile
      sm.g.Bs[ac + 1][ar] = f2bf(vb.y);
      sm.g.Bs[ac + 2][ar] = f2bf(vb.z);
      sm.g.Bs[ac + 3][ar] = f2bf(vb.w);
      __syncthreads();
      if (kt + 1 < NT) ld((kt + 1) * BK, va0n, va1n, vbn);
      const short8 af = *(const short8*)&sm.g.As[w * 16 + lm][q * 8];
#pragma unroll
      for (int nt = 0; nt < 2; ++nt) {
        const short8 bf = *(const short8*)&sm.g.Bs[nt * 16 + lm][q * 8];
        acc[nt] = __builtin_amdgcn_mfma_f32_16x16x32_bf16(af, bf, acc[nt], 0, 0, 0);
      }
      __syncthreads();
      va0 = va0n; va1 = va1n; vb = vbn;
    }
    const int row0 = m0 + w * 16 + q * 4;
#pragma unroll
    for (int nt = 0; nt < 2; ++nt) {
      const int col = n0 + nt * 16 + lm;
      const float bv = b1[col];
#pragma unroll
      for (int r = 0; r < 4; ++r)
        if (row0 + r < N_NODES)
          h1b[(size_t)(row0 + r) * N + col] = f2bf(fmaxf(acc[nt][r] + bv, 0.f));
    }
    return;
  }

  // ----- prep blocks: [W2;b2]@Wg -> WfT + bfuse, and cursor zeroing -----
  const int bp = b - 628;  // 0..11
  {
    const int flat = bp * 256 + t;
    if (flat < (N_NODES + 3) / 4) ((int4*)cursor)[flat] = make_int4(0, 0, 0, 0);
  }
  const int bx = bp >> 2, by = bp & 3;
  const int tx = t & 15, ty = t >> 4;
  const int m0 = bx * 64, n0 = by * 64;
  const int ar = t >> 2, ac4 = (t & 3) * 4;
  const int br = t >> 4, bc4 = (t & 15) * 4;
  const int arow = m0 + ar;
  float acc[4][4] = {};
  float4 av, bv, avn, bvn;
  auto gload = [&](int k0, float4& a4, float4& b4) {
    if (arow < DIM_HID)       a4 = *(const float4*)(W2 + (size_t)arow * DIM_HID + k0 + ac4);
    else if (arow == DIM_HID) a4 = *(const float4*)(b2 + k0 + ac4);
    else                      a4 = make_float4(0.f, 0.f, 0.f, 0.f);
    b4 = *(const float4*)(Wg + (size_t)(k0 + br) * HC + n0 + bc4);
  };
  gload(0, av, bv);
  for (int k0 = 0; k0 < DIM_HID; k0 += 16) {
    sm.p.Ast[ac4 + 0][ar] = av.x; sm.p.Ast[ac4 + 1][ar] = av.y;
    sm.p.Ast[ac4 + 2][ar] = av.z; sm.p.Ast[ac4 + 3][ar] = av.w;
    *(float4*)&sm.p.Bsf[br][bc4] = bv;
    __syncthreads();
    if (k0 + 16 < DIM_HID) gload(k0 + 16, avn, bvn);
#pragma unroll
    for (int kk = 0; kk < 16; ++kk) {
      const float4 a = *(const float4*)&sm.p.Ast[kk][ty * 4];
      const float4 bq = *(const float4*)&sm.p.Bsf[kk][tx * 4];
      const float as[4] = {a.x, a.y, a.z, a.w};
      const float bs[4] = {bq.x, bq.y, bq.z, bq.w};
#pragma unroll
      for (int i = 0; i < 4; ++i)
#pragma unroll
        for (int j = 0; j < 4; ++j) acc[i][j] = fmaf(as[i], bs[j], acc[i][j]);
    }
    __syncthreads();
    av = avn; bv = bvn;
  }
#pragma unroll
  for (int i = 0; i < 4; ++i) {
    const int row = m0 + ty * 4 + i;
#pragma unroll
    for (int j = 0; j < 4; ++j) {
      const int col = n0 + tx * 4 + j;
      if (row < DIM_HID)       WfT[(size_t)col * DIM_HID + row] = f2bf(acc[i][j]);
      else if (row == DIM_HID) bfuse[col] = acc[i][j];
    }
  }
}

// ---------------------------------------------------------------------------
// gemm2: g = bf16(h1b @ Wfuse + bfuse), BM=BN=64 BK=32, ATT epilogue.
// Preamble: slot-96 CSR scatter (cursor zeroed in fused1's prep blocks).
// ---------------------------------------------------------------------------
__global__ __launch_bounds__(256) void gemm2_kernel(
    const unsigned short* __restrict__ h1b, const unsigned short* __restrict__ WfT,
    const float* __restrict__ bfuse, unsigned short* __restrict__ g,
    const float* __restrict__ att_src, const float* __restrict__ att_dst,
    float* __restrict__ a_src, float* __restrict__ a_dst,
    const int* __restrict__ e_src, const int* __restrict__ e_dst,
    int* __restrict__ cursor, int* __restrict__ src_sorted) {
  constexpr int K = DIM_HID, N = HC, BK = 32;
  __shared__ unsigned short As[64][48];
  __shared__ unsigned short Bs[64][48];
  const int t = threadIdx.x;
  {
    const int nthr = gridDim.x * gridDim.y * 256;
    const int flat = (blockIdx.y * gridDim.x + blockIdx.x) * 256 + t;
    for (int id = flat; id < N_EDGES + N_NODES; id += nthr) {
      int s, d;
      if (id < N_EDGES) { s = e_src[id]; d = e_dst[id]; }
      else              { s = d = id - N_EDGES; }
      src_sorted[d * SLOT + atomicAdd(&cursor[d], 1)] = s;
    }
  }
  const int m0 = blockIdx.x * 64, n0 = blockIdx.y * 64;
  const int w = t >> 6, L = t & 63, lm = L & 15, q = L >> 4;
  floatx4 acc[4] = {};
  uint4 ab, abn, bb, bbn;
  auto ld = [&](int kb, uint4& va, uint4& vb) {
    va = *(const uint4*)(h1b + (size_t)(m0 + (t >> 2)) * K + kb + (t & 3) * 8);
    vb = *(const uint4*)(WfT + (size_t)(n0 + (t >> 2)) * K + kb + (t & 3) * 8);
  };
  constexpr int NT = K / BK;  // 4
  ld(0, ab, bb);
  for (int kt = 0; kt < NT; ++kt) {
    *(uint4*)&As[t >> 2][(t & 3) * 8] = ab;
    *(uint4*)&Bs[t >> 2][(t & 3) * 8] = bb;
    __syncthreads();
    if (kt + 1 < NT) ld((kt + 1) * BK, abn, bbn);
    const short8 af = *(const short8*)&As[w * 16 + lm][q * 8];
#pragma unroll
    for (int nt = 0; nt < 4; ++nt) {
      const short8 bf = *(const short8*)&Bs[nt * 16 + lm][q * 8];
      acc[nt] = __builtin_amdgcn_mfma_f32_16x16x32_bf16(af, bf, acc[nt], 0, 0, 0);
    }
    __syncthreads();
    ab = abn; bb = bbn;
  }
  const int row0 = m0 + w * 16 + q * 4;
  const int hh = n0 >> 6;
  float ps[4] = {}, pd[4] = {};
#pragma unroll
  for (int nt = 0; nt < 4; ++nt) {
    const int col = n0 + nt * 16 + lm;
    const float bv = bfuse[col];
    const float as_c = att_src[hh * 64 + nt * 16 + lm];
    const float ad_c = att_dst[hh * 64 + nt * 16 + lm];
#pragma unroll
    for (int r = 0; r < 4; ++r) {
      const float gv = acc[nt][r] + bv;
      if (row0 + r < N_NODES) g[(size_t)(row0 + r) * N + col] = f2bf(gv);
      ps[r] = fmaf(gv, as_c, ps[r]);
      pd[r] = fmaf(gv, ad_c, pd[r]);
    }
  }
#pragma unroll
  for (int r = 0; r < 4; ++r) {
#pragma unroll
    for (int off = 1; off < 16; off <<= 1) {
      ps[r] += __shfl_xor(ps[r], off);
      pd[r] += __shfl_xor(pd[r], off);
    }
    if (lm == 0 && row0 + r < N_NODES) {
      a_src[(row0 + r) * 4 + hh] = ps[r];
      a_dst[(row0 + r) * 4 + hh] = pd[r];
    }
  }
}

// ---------------------------------------------------------------------------
// Aggregate: one wave per node, zero barriers / zero LDS (R11/R12 winner).
// start = node*SLOT, end = start + cursor[node] (slot-96 CSR).
// ---------------------------------------------------------------------------
__global__ __launch_bounds__(256) void aggregate_kernel(
    const unsigned short* __restrict__ g, const float* __restrict__ a_src,
    const float* __restrict__ a_dst, const int* __restrict__ cursor,
    const int* __restrict__ src_sorted, const float* __restrict__ bias_g,
    float* __restrict__ out) {
  const int wv   = threadIdx.x >> 6;
  const int lane = threadIdx.x & 63;
  const int node = blockIdx.x * 4 + wv;
  if (node >= N_NODES) return;
  const int e2 = lane >> 5;     // edge parity
  const int c8 = lane & 31;     // chan-octet (chans c8*8 .. +7)
  const int h  = c8 >> 3;       // head of those chans
  const int start = node * SLOT;
  const int end   = start + cursor[node];
  const float4 ad = *(const float4*)(a_dst + node * 4);

  float a[8] = {};
  float s_loc = 0.f;
  for (int base = start; base < end; base += 64) {
    const int rem = min(64, end - base);
    int   sidxL = 0;
    float w0 = 0.f, w1 = 0.f, w2 = 0.f, w3 = 0.f;
    if (lane < rem) {
      sidxL = src_sorted[base + lane];
      const float4 as4 = *(const float4*)(a_src + sidxL * 4);
      float e0 = as4.x + ad.x; e0 = (e0 > 0.f) ? e0 : NEG_SLOPE * e0;
      float e1 = as4.y + ad.y; e1 = (e1 > 0.f) ? e1 : NEG_SLOPE * e1;
      float ee = as4.z + ad.z; ee = (ee > 0.f) ? ee : NEG_SLOPE * ee;
      float e3 = as4.w + ad.w; e3 = (e3 > 0.f) ? e3 : NEG_SLOPE * e3;
      w0 = __expf(e0); w1 = __expf(e1); w2 = __expf(ee); w3 = __expf(e3);
    }
    const int half = (rem + 1) >> 1;
#pragma unroll 4
    for (int k = 0; k < half; ++k) {
      const int j  = 2 * k + e2;
      const int js = (j < rem) ? j : (rem - 1);      // keep shfl src valid
      const int sj = __shfl(sidxL, js);
      const float f0 = __shfl(w0, js), f1 = __shfl(w1, js);
      const float f2 = __shfl(w2, js), f3 = __shfl(w3, js);
      float w = (h & 2) ? ((h & 1) ? f3 : f2) : ((h & 1) ? f1 : f0);
      if (j >= rem) w = 0.f;                          // masked tail edge
      const uint4 gv = *(const uint4*)(g + (size_t)sj * HC + c8 * 8);
      s_loc += w;
      a[0] = fmaf(w, __uint_as_float(gv.x << 16), a[0]);
      a[1] = fmaf(w, __uint_as_float(gv.x & 0xFFFF0000u), a[1]);
      a[2] = fmaf(w, __uint_as_float(gv.y << 16), a[2]);
      a[3] = fmaf(w, __uint_as_float(gv.y & 0xFFFF0000u), a[3]);
      a[4] = fmaf(w, __uint_as_float(gv.z << 16), a[4]);
      a[5] = fmaf(w, __uint_as_float(gv.z & 0xFFFF0000u), a[5]);
      a[6] = fmaf(w, __uint_as_float(gv.w << 16), a[6]);
      a[7] = fmaf(w, __uint_as_float(gv.w & 0xFFFF0000u), a[7]);
    }
  }
#pragma unroll
  for (int k = 0; k < 8; ++k) a[k] += __shfl_xor(a[k], 32);
  s_loc += __shfl_xor(s_loc, 32);
  if (e2 == 0) {
    const float inv = 1.f / s_loc;
    const float4 b0 = *(const float4*)(bias_g + c8 * 8);
    const float4 b1v = *(const float4*)(bias_g + c8 * 8 + 4);
    float4 o0, o1;
    o0.x = a[0] * inv + b0.x;  o0.y = a[1] * inv + b0.y;
    o0.z = a[2] * inv + b0.z;  o0.w = a[3] * inv + b0.w;
    o1.x = a[4] * inv + b1v.x; o1.y = a[5] * inv + b1v.y;
    o1.z = a[6] * inv + b1v.z; o1.w = a[7] * inv + b1v.w;
    float* op = out + (size_t)node * HC + c8 * 8;
    *(float4*)op = o0;
    *(float4*)(op + 4) = o1;
  }
}

// ---------------------------------------------------------------------------
extern "C" void kernel_launch(void* const* d_in, const int* in_sizes, int n_in,
                              void* d_out, int out_size, void* d_ws, size_t ws_size,
                              hipStream_t stream) {
  const float* x       = (const float*)d_in[0];
  const int*   ei      = (const int*)d_in[1];   // [2,E] int32: src then dst
  const float* W1      = (const float*)d_in[2];
  const float* b1      = (const float*)d_in[3];
  const float* W2      = (const float*)d_in[4];
  const float* b2      = (const float*)d_in[5];
  const float* Wg      = (const float*)d_in[6];
  const float* att_src = (const float*)d_in[7];
  const float* att_dst = (const float*)d_in[8];
  const float* bias_g  = (const float*)d_in[9];
  float* out = (float*)d_out;

  char* ws = (char*)d_ws;
  unsigned short* h1b = (unsigned short*)ws; ws += (size_t)(N_NODES + 64) * DIM_HID * 2;
  unsigned short* g   = (unsigned short*)ws; ws += (size_t)N_NODES * HC * 2;
  unsigned short* WfT = (unsigned short*)ws; ws += (size_t)HC * DIM_HID * 2;
  float* bfuse   = (float*)ws; ws += (size_t)HC * 4;
  float* a_src   = (float*)ws; ws += (size_t)N_NODES * 4 * 4;
  float* a_dst   = (float*)ws; ws += (size_t)N_NODES * 4 * 4;
  int* cursor    = (int*)ws;   ws += (size_t)N_NODES * 4;
  int* src_sorted= (int*)ws;   ws += (size_t)N_NODES * SLOT * 4;

  const dim3 blk(256);
  // 1. gemm1 (x + W1 staged from natural layouts) + prep GEMM + cursor zero
  fused1_kernel<<<640, blk, 0, stream>>>(
      x, W1, b1, W2, Wg, b2, h1b, WfT, bfuse, cursor);
  // 2. fused layer2+GAT MFMA -> bf16 g, attention epilogue, + slot-96 scatter
  gemm2_kernel<<<dim3(157, 4), blk, 0, stream>>>(
      h1b, WfT, bfuse, g, att_src, att_dst, a_src, a_dst,
      ei, ei + N_EDGES, cursor, src_sorted);
  // 3. segment softmax + weighted aggregate (wave per node)
  aggregate_kernel<<<(N_NODES + 3) / 4, blk, 0, stream>>>(
      g, a_src, a_dst, cursor, src_sorted, bias_g, out);
}